// Round 9
// baseline (42.028 us; speedup 1.0000x reference)
//
#include <hip/hip_runtime.h>

// out[b, m] = sum_n exp(-0.5 * ||inputs[b,n] - stars[m]||^2)
// B=32, N=4096, M=1024, D=3, fp32 in/out.
//
// exp(-0.5*d2) = 2^(q + Sx*x + Sy*y + Sz*z + K), q = -C2*||x||^2 per point,
// K = -C2*||s||^2, S = log2(e)*s.
// R8 post-mortem: every prior structure paid a serialized per-CU pipe
// (LDS 10.2us / global latency / readlane). This round the point stream —
// which is wave-uniform — lives in SGPRs via explicit s_load_dwordx16:
//   - batch of 16 points = 48 dwords = 3x s_load_dwordx16 in ONE asm block
//     with s_waitcnt lgkmcnt(0) inside (no reorder hazard), "=&s" early-
//     clobber so loads can't clobber the base pointer pair.
//   - hot math: per term 3 fma (one SGPR coord each) + add(q) + v_exp + add.
//   - zero LDS, zero syncthreads, zero VALU on addressing.
// Floor: 2048 wave-terms/SIMD * ~12cy = 10.2us, trans+SMEM overlapped.

typedef float f32x16 __attribute__((ext_vector_type(16)));

#define NB 32
#define NN 4096
#define NM 1024
#define NCHUNK 64               // blocks per batch along N
#define NPB (NN / NCHUNK)       // 64 points per block
#define TPB 256                 // threads per block (4 waves)
#define MPT (NM / TPB)          // 4 stars per thread
#define NBATCH 4                // 16 points per batch

__device__ __forceinline__ float exp2_hw(float x) {
    float r;
    asm("v_exp_f32 %0, %1" : "=v"(r) : "v"(x));
    return r;
}

// flat dword f of the 48-dword batch, f compile-time constant after unroll
#define GETF(f) ((f) < 16 ? PA[(f)] : ((f) < 32 ? PB[(f) - 16] : PC[(f) - 32]))

__global__ __launch_bounds__(TPB, 8) void gau_part(const float* __restrict__ inputs,
                                                   const float* __restrict__ stars,
                                                   float* __restrict__ part) {
    constexpr float C2  = 0.72134752044448169f;  // 0.5*log2(e)
    constexpr float L2E = 1.44269504088896340f;  // log2(e)

    const int b     = blockIdx.x / NCHUNK;
    const int chunk = blockIdx.x % NCHUNK;
    const int t     = threadIdx.x;

    // Per-thread star constants (VGPRs: 16 + 4 acc)
    float Sx[MPT], Sy[MPT], Sz[MPT], K[MPT], acc[MPT];
#pragma unroll
    for (int k = 0; k < MPT; ++k) {
        int m = t + k * TPB;
        float sx = stars[3 * m + 0];
        float sy = stars[3 * m + 1];
        float sz = stars[3 * m + 2];
        Sx[k] = L2E * sx;
        Sy[k] = L2E * sy;
        Sz[k] = L2E * sz;
        K[k]  = -C2 * (sx * sx + sy * sy + sz * sz);
        acc[k] = 0.0f;
    }

    // Wave-uniform point stream, read on the SMEM pipe into SGPRs.
    const float* base = inputs + ((size_t)b * NN + (size_t)chunk * NPB) * 3;

#pragma unroll 1
    for (int batch = 0; batch < NBATCH; ++batch) {
        const float* pb = base + batch * 48;  // uniform -> SGPR pair
        f32x16 PA, PB, PC;
        asm volatile(
            "s_load_dwordx16 %0, %3, 0\n\t"
            "s_load_dwordx16 %1, %3, 64\n\t"
            "s_load_dwordx16 %2, %3, 128\n\t"
            "s_waitcnt lgkmcnt(0)"
            : "=&s"(PA), "=&s"(PB), "=&s"(PC)
            : "s"(pb));
#pragma unroll
        for (int p = 0; p < 16; ++p) {
            float x = GETF(3 * p + 0);
            float y = GETF(3 * p + 1);
            float z = GETF(3 * p + 2);
            float q = -C2 * x * x - C2 * y * y - C2 * z * z;
#pragma unroll
            for (int k = 0; k < MPT; ++k) {
                float u = fmaf(z, Sz[k], K[k]);
                u = fmaf(y, Sy[k], u);
                u = fmaf(x, Sx[k], u);
                acc[k] += exp2_hw(q + u);
            }
        }
    }

    // Coalesced partial store: part[(b*NCHUNK + chunk)*NM + m]
    float* pbo = part + ((size_t)b * NCHUNK + chunk) * NM;
#pragma unroll
    for (int k = 0; k < MPT; ++k) {
        pbo[t + k * TPB] = acc[k];
    }
}

__global__ __launch_bounds__(256) void gau_reduce(const float* __restrict__ part,
                                                  float* __restrict__ out) {
    const int o = blockIdx.x * 256 + threadIdx.x;  // o = b*NM + m, 32K total
    const int b = o >> 10;
    const int m = o & (NM - 1);
    const float* pb = part + (size_t)b * NCHUNK * NM + m;
    float s = 0.0f;
#pragma unroll
    for (int c = 0; c < NCHUNK; ++c) {
        s += pb[(size_t)c * NM];  // adjacent lanes -> adjacent m: coalesced
    }
    out[o] = s;
}

extern "C" void kernel_launch(void* const* d_in, const int* in_sizes, int n_in,
                              void* d_out, int out_size, void* d_ws, size_t ws_size,
                              hipStream_t stream) {
    const float* inputs = (const float*)d_in[0];  // (32, 4096, 3)
    const float* stars  = (const float*)d_in[1];  // (1024, 3)
    float* out  = (float*)d_out;                  // (32, 1024)
    float* part = (float*)d_ws;                   // (32*64, 1024) = 8 MB

    gau_part<<<NB * NCHUNK, TPB, 0, stream>>>(inputs, stars, part);
    gau_reduce<<<(NB * NM) / 256, 256, 0, stream>>>(part, out);
}

// Round 10
// 32.350 us; speedup vs baseline: 1.2991x; 1.2991x over previous
//
#include <hip/hip_runtime.h>

// out[b, m] = sum_n exp(-0.5 * ||inputs[b,n] - stars[m]||^2)
// B=32, N=4096, M=1024, D=3, fp32 in/out.
//
// exp(-0.5*d2) = E_n * 2^(Sx*x + Sy*y + Sz*z + K), E_n = 2^(-C2*||x||^2).
// R9 post-mortem: all nine rounds fit  dur ~= issue_model + ~19us constant.
// Candidates for the constant: (a) ~10us/launch x 2 kernels, (b) LDS-pipe
// serialization (R5: 2048 b128-broadcasts/CU = 10.2us).
// This round discriminates: wave-owns-all-stars structure cuts LDS traffic
// 4x while keeping the 8.5us VALU floor:
//   - TPB=128 (2 waves); each wave covers ALL 1024 stars, MPT=16 per lane
//   - each wave processes its own 64-point half of the block's 128 points
//   - per point per wave: ONE ds_read_b128 amortized over 16 stars
//   - 16 independent star-chains per point -> ILP hides exp latency at
//     2 waves/SIMD (1024 blocks, 4/CU)
//   - 2-wave LDS combine -> one 4KB partial row per block (4MB total)
// If LDS was the residual: ~14-16us. If launch floor: ~27 (-> next round
// goes single-launch).

#define NB 32
#define NBLK 32                 // blocks per batch along N
#define NPB 128                 // points per block
#define NPW 64                  // points per wave
#define TPB 128                 // threads per block (2 waves)
#define MPT 16                  // stars per lane (64 lanes x 16 = 1024)

__device__ __forceinline__ float exp2_hw(float x) {
    float r;
    asm("v_exp_f32 %0, %1" : "=v"(r) : "v"(x));
    return r;
}

__global__ __launch_bounds__(TPB, 2) void gau_part(const float* __restrict__ inputs,
                                                   const float* __restrict__ stars,
                                                   float* __restrict__ part) {
    constexpr float C2  = 0.72134752044448169f;  // 0.5*log2(e)
    constexpr float L2E = 1.44269504088896340f;  // log2(e)

    const int b    = blockIdx.x / NBLK;
    const int blk  = blockIdx.x % NBLK;
    const int t    = threadIdx.x;
    const int wave = t >> 6;
    const int lane = t & 63;

    __shared__ float4 pts[NPB];        // (x, y, z, E)
    __shared__ float  part_lds[1024];  // 2-wave combine buffer

    // Stage 128 points (one per thread), precompute E.
    {
        const float* p = inputs + ((size_t)b * 4096 + (size_t)blk * NPB + t) * 3;
        float x = p[0], y = p[1], z = p[2];
        float q = -C2 * x * x - C2 * y * y - C2 * z * z;
        pts[t] = make_float4(x, y, z, exp2_hw(q));
    }

    // Per-lane star constants: m = lane*MPT + k (contiguous per lane).
    float Sx[MPT], Sy[MPT], Sz[MPT], K[MPT], acc[MPT];
#pragma unroll
    for (int k = 0; k < MPT; ++k) {
        int m = lane * MPT + k;
        float sx = stars[3 * m + 0];
        float sy = stars[3 * m + 1];
        float sz = stars[3 * m + 2];
        Sx[k] = L2E * sx;
        Sy[k] = L2E * sy;
        Sz[k] = L2E * sz;
        K[k]  = -C2 * (sx * sx + sy * sy + sz * sz);
        acc[k] = 0.0f;
    }

    __syncthreads();

    // Hot loop: wave w owns points [w*64, w*64+64); one broadcast b128 read
    // per point, amortized over 16 stars; 16 independent chains -> ILP.
    const int pbase = wave * NPW;
#pragma unroll 4
    for (int i = 0; i < NPW; ++i) {
        float4 p = pts[pbase + i];
#pragma unroll
        for (int k = 0; k < MPT; ++k) {
            float u = fmaf(p.z, Sz[k], K[k]);
            u = fmaf(p.y, Sy[k], u);
            u = fmaf(p.x, Sx[k], u);
            acc[k] = fmaf(p.w, exp2_hw(u), acc[k]);
        }
    }

    // Combine the two waves' partials in LDS, wave 0 writes the block row.
    if (wave == 1) {
#pragma unroll
        for (int c = 0; c < MPT / 4; ++c) {
            *(float4*)&part_lds[lane * MPT + 4 * c] =
                make_float4(acc[4 * c], acc[4 * c + 1], acc[4 * c + 2], acc[4 * c + 3]);
        }
    }
    __syncthreads();
    if (wave == 0) {
        float* prow = part + (size_t)blockIdx.x * 1024;
#pragma unroll
        for (int c = 0; c < MPT / 4; ++c) {
            float4 o = *(float4*)&part_lds[lane * MPT + 4 * c];
            o.x += acc[4 * c];
            o.y += acc[4 * c + 1];
            o.z += acc[4 * c + 2];
            o.w += acc[4 * c + 3];
            *(float4*)&prow[lane * MPT + 4 * c] = o;  // coalesced 4KB row
        }
    }
}

__global__ __launch_bounds__(256) void gau_reduce(const float* __restrict__ part,
                                                  float* __restrict__ out) {
    const int o = blockIdx.x * 256 + threadIdx.x;  // o = b*1024 + m, 32K total
    const int b = o >> 10;
    const int m = o & 1023;
    const float* pb = part + (size_t)b * NBLK * 1024 + m;
    float s = 0.0f;
#pragma unroll
    for (int c = 0; c < NBLK; ++c) {
        s += pb[(size_t)c * 1024];  // adjacent lanes -> adjacent m: coalesced
    }
    out[o] = s;
}

extern "C" void kernel_launch(void* const* d_in, const int* in_sizes, int n_in,
                              void* d_out, int out_size, void* d_ws, size_t ws_size,
                              hipStream_t stream) {
    const float* inputs = (const float*)d_in[0];  // (32, 4096, 3)
    const float* stars  = (const float*)d_in[1];  // (1024, 3)
    float* out  = (float*)d_out;                  // (32, 1024)
    float* part = (float*)d_ws;                   // (1024, 1024) = 4 MB

    gau_part<<<NB * NBLK, TPB, 0, stream>>>(inputs, stars, part);
    gau_reduce<<<(NB * 1024) / 256, 256, 0, stream>>>(part, out);
}

// Round 11
// 29.884 us; speedup vs baseline: 1.4063x; 1.0825x over previous
//
#include <hip/hip_runtime.h>

// out[b, m] = sum_n exp(-0.5 * ||inputs[b,n] - stars[m]||^2)
// B=32, N=4096, M=1024, D=3, fp32 in/out.
//
// exp(-0.5*d2) = E_n * 2^(Sx*x + Sy*y + Sz*z + K), E_n = 2^(-C2*||x||^2).
// R10 post-mortem: LDS-pipe hypothesis refuted (4x less LDS traffic -> slower).
// All rounds fit dur = issue_cycles + ~18.9us, structure-invariant. Last
// kernel-controllable suspect: the 2-launch dependent structure (drain +
// second dispatch + graph node). This round: SINGLE LAUNCH, no reduction
// kernel, no atomics, no zeroing:
//   - grid = 32 b x 32 mchunks = 1024 blocks (4/CU, 4 waves/SIMD like R5)
//   - block owns 32 m's x ALL 4096 points -> out written directly
//   - thread: mg=t&3 -> 8 stars (MPT=8, 5.6 instr/term), pg=t>>2 -> 64
//     interleaved points (wave reads 192B contiguous/iter, L1-resident)
//   - reduce: 4 shfl_xor (4/8/16/32) + 512B LDS cross-wave + 128B store
// Per point: 4 VALU (q) + 1 exp (E) + 8 x (3 fma + exp + fma).

#define NB 32
#define NM 1024
#define NN 4096
#define TPB 256
#define MCHUNK 32               // m's per block
#define MPT 8                   // stars per thread
#define NPT 64                  // points per thread (interleaved stride 64)

__device__ __forceinline__ float exp2_hw(float x) {
    float r;
    asm("v_exp_f32 %0, %1" : "=v"(r) : "v"(x));
    return r;
}

__global__ __launch_bounds__(TPB, 4) void gau_single(const float* __restrict__ inputs,
                                                     const float* __restrict__ stars,
                                                     float* __restrict__ out) {
    constexpr float C2  = 0.72134752044448169f;  // 0.5*log2(e)
    constexpr float L2E = 1.44269504088896340f;  // log2(e)

    const int b  = blockIdx.x >> 5;        // batch
    const int mc = blockIdx.x & 31;        // m-chunk of 32
    const int t  = threadIdx.x;
    const int wv = t >> 6;                 // wave 0..3
    const int mg = t & 3;                  // m-group within chunk
    const int pg = t >> 2;                 // point-group 0..63

    __shared__ float red[4][MCHUNK];       // cross-wave combine (512 B)

    // Per-thread star constants: m = mc*32 + mg*8 + k
    float Sx[MPT], Sy[MPT], Sz[MPT], K[MPT], acc[MPT];
#pragma unroll
    for (int k = 0; k < MPT; ++k) {
        int m = mc * MCHUNK + mg * MPT + k;
        float sx = stars[3 * m + 0];
        float sy = stars[3 * m + 1];
        float sz = stars[3 * m + 2];
        Sx[k] = L2E * sx;
        Sy[k] = L2E * sy;
        Sz[k] = L2E * sz;
        K[k]  = -C2 * (sx * sx + sy * sy + sz * sz);
        acc[k] = 0.0f;
    }

    // Hot loop: thread's point at iter i is i*64 + pg (wave reads 16
    // consecutive points = 192 B contiguous; 4-lane broadcast per point).
    const float* base = inputs + (size_t)b * NN * 3;
#pragma unroll 4
    for (int i = 0; i < NPT; ++i) {
        const float* p = base + (size_t)(i * 64 + pg) * 3;
        float x = p[0], y = p[1], z = p[2];
        float s2 = x * x;
        s2 = fmaf(y, y, s2);
        s2 = fmaf(z, z, s2);
        float E = exp2_hw(-C2 * s2);
#pragma unroll
        for (int k = 0; k < MPT; ++k) {
            float u = fmaf(z, Sz[k], K[k]);
            u = fmaf(y, Sy[k], u);
            u = fmaf(x, Sx[k], u);
            acc[k] = fmaf(E, exp2_hw(u), acc[k]);
        }
    }

    // Within-wave reduce over the 16 lanes sharing mg (lanes differ in pg bits)
#pragma unroll
    for (int k = 0; k < MPT; ++k) {
        acc[k] += __shfl_xor(acc[k], 4, 64);
        acc[k] += __shfl_xor(acc[k], 8, 64);
        acc[k] += __shfl_xor(acc[k], 16, 64);
        acc[k] += __shfl_xor(acc[k], 32, 64);
    }

    // Lane mg (0..3) of each wave holds the wave's sum for its 8 m's.
    if ((t & 63) < 4) {
#pragma unroll
        for (int k = 0; k < MPT; ++k) {
            red[wv][mg * MPT + k] = acc[k];
        }
    }
    __syncthreads();

    // First 32 threads: combine 4 waves, write out[b*1024 + mc*32 + j].
    if (t < MCHUNK) {
        float s = red[0][t] + red[1][t] + red[2][t] + red[3][t];
        out[(size_t)b * NM + mc * MCHUNK + t] = s;
    }
}

extern "C" void kernel_launch(void* const* d_in, const int* in_sizes, int n_in,
                              void* d_out, int out_size, void* d_ws, size_t ws_size,
                              hipStream_t stream) {
    const float* inputs = (const float*)d_in[0];  // (32, 4096, 3)
    const float* stars  = (const float*)d_in[1];  // (1024, 3)
    float* out = (float*)d_out;                   // (32, 1024)

    gau_single<<<NB * 32, TPB, 0, stream>>>(inputs, stars, out);
}